// Round 1
// baseline (1810.578 us; speedup 1.0000x reference)
//
#include <hip/hip_runtime.h>
#include <hip/hip_bf16.h>

// Problem constants
// B=4, S=2048, D_MODEL=1024, NS=4 scales (1,2,4,8), E=256, H=4, DK=64
// out = [fused (4*2048*1024)] ++ [w0 (4*2048*2048)]

// ---------------------------------------------------------------------------
// Generic tiled fp32 GEMM: C[M,N] = gatherA[M,K] @ W[K,N] + bias
// A row m address: A + (m/rows_per_batch)*a_batch_stride + (m%rows_per_batch)*a_row_stride
// 64x64 tile, BK=32, 256 threads, 4x4 per thread.
// ---------------------------------------------------------------------------
__global__ __launch_bounds__(256) void gemm_bias_kernel(
    const float* __restrict__ A, long a_batch_stride, int rows_per_batch, int a_row_stride,
    const float* __restrict__ W, int w_row_stride,
    const float* __restrict__ bias,
    float* __restrict__ C, int c_row_stride,
    int M, int N, int K)
{
    __shared__ float As[32][68];  // [k][m], +4 pad keeps 16B alignment
    __shared__ float Ws[32][68];  // [k][n]
    const int tid = threadIdx.x;
    const int tx = tid & 15, ty = tid >> 4;
    const int m0 = blockIdx.x * 64, n0 = blockIdx.y * 64;
    float acc[4][4] = {};

    for (int k0 = 0; k0 < K; k0 += 32) {
        #pragma unroll
        for (int it = 0; it < 8; ++it) {
            int f = tid + it * 256;
            int r = f >> 5, c = f & 31;      // r: 0..63 (m), c: 0..31 (k)
            int m = m0 + r;
            float v = 0.f;
            if (m < M) {
                int b = m / rows_per_batch;
                int t = m - b * rows_per_batch;
                v = A[b * a_batch_stride + (long)t * a_row_stride + k0 + c];
            }
            As[c][r] = v;
        }
        #pragma unroll
        for (int it = 0; it < 8; ++it) {
            int f = tid + it * 256;
            int r = f >> 6, c = f & 63;      // r: 0..31 (k), c: 0..63 (n)
            Ws[r][c] = W[(long)(k0 + r) * w_row_stride + n0 + c];
        }
        __syncthreads();
        #pragma unroll
        for (int kk = 0; kk < 32; ++kk) {
            float4 a4 = *(const float4*)&As[kk][ty * 4];
            float4 w4 = *(const float4*)&Ws[kk][tx * 4];
            float a[4] = {a4.x, a4.y, a4.z, a4.w};
            float w[4] = {w4.x, w4.y, w4.z, w4.w};
            #pragma unroll
            for (int i = 0; i < 4; ++i)
                #pragma unroll
                for (int j = 0; j < 4; ++j)
                    acc[i][j] += a[i] * w[j];
        }
        __syncthreads();
    }

    float4 b4 = *(const float4*)&bias[n0 + tx * 4];
    float bb[4] = {b4.x, b4.y, b4.z, b4.w};
    #pragma unroll
    for (int i = 0; i < 4; ++i) {
        int m = m0 + ty * 4 + i;
        if (m >= M) continue;
        float4 o4;
        o4.x = acc[i][0] + bb[0];
        o4.y = acc[i][1] + bb[1];
        o4.z = acc[i][2] + bb[2];
        o4.w = acc[i][3] + bb[3];
        *(float4*)&C[(long)m * c_row_stride + n0 + tx * 4] = o4;
    }
}

// ---------------------------------------------------------------------------
// Scores: S[bh, q, k] = (Q[bh,q,:] . K[bh,k,:]) * 0.125
// qkv rows: (b*L + t)*768, q at col h*64, k at col 256+h*64
// grid: (L/64, L/64, 16)
// ---------------------------------------------------------------------------
__global__ __launch_bounds__(256) void scores_kernel(
    const float* __restrict__ qkv, float* __restrict__ probs, int L)
{
    __shared__ float Qs[64][68];  // [d][q]
    __shared__ float Ks[64][68];  // [d][k]
    const int tid = threadIdx.x;
    const int tx = tid & 15, ty = tid >> 4;
    const int q0 = blockIdx.x * 64, k0 = blockIdx.y * 64;
    const int bh = blockIdx.z;
    const int b = bh >> 2, h = bh & 3;
    const float* qbase = qkv + (long)(b * L) * 768 + h * 64;
    const float* kbase = qbase + 256;

    #pragma unroll
    for (int it = 0; it < 16; ++it) {
        int f = tid + it * 256;
        int r = f >> 6, d = f & 63;
        Qs[d][r] = qbase[(long)(q0 + r) * 768 + d];
        Ks[d][r] = kbase[(long)(k0 + r) * 768 + d];
    }
    __syncthreads();

    float acc[4][4] = {};
    #pragma unroll
    for (int d = 0; d < 64; ++d) {
        float4 a4 = *(const float4*)&Qs[d][ty * 4];
        float4 k4 = *(const float4*)&Ks[d][tx * 4];
        float a[4] = {a4.x, a4.y, a4.z, a4.w};
        float w[4] = {k4.x, k4.y, k4.z, k4.w};
        #pragma unroll
        for (int i = 0; i < 4; ++i)
            #pragma unroll
            for (int j = 0; j < 4; ++j)
                acc[i][j] += a[i] * w[j];
    }

    #pragma unroll
    for (int i = 0; i < 4; ++i) {
        long row = (long)bh * L + q0 + ty * 4 + i;
        float4 o4;
        o4.x = acc[i][0] * 0.125f;
        o4.y = acc[i][1] * 0.125f;
        o4.z = acc[i][2] * 0.125f;
        o4.w = acc[i][3] * 0.125f;
        *(float4*)&probs[row * L + k0 + tx * 4] = o4;
    }
}

// ---------------------------------------------------------------------------
// Row softmax in place. grid: (16*L) rows, 256 threads. L in {256,512,1024,2048}.
// ---------------------------------------------------------------------------
__global__ __launch_bounds__(256) void softmax_kernel(float* __restrict__ probs, int L)
{
    long row = blockIdx.x;
    float* p = probs + row * (long)L;
    const int tid = threadIdx.x;
    const int n = L >> 8;  // elems per thread, <= 8
    float v[8];
    float mx = -1e30f;
    #pragma unroll
    for (int j = 0; j < 8; ++j)
        if (j < n) { v[j] = p[tid + (j << 8)]; mx = fmaxf(mx, v[j]); }

    #pragma unroll
    for (int off = 32; off; off >>= 1) mx = fmaxf(mx, __shfl_xor(mx, off));
    __shared__ float redm[4], reds[4];
    int wid = tid >> 6;
    if ((tid & 63) == 0) redm[wid] = mx;
    __syncthreads();
    mx = fmaxf(fmaxf(redm[0], redm[1]), fmaxf(redm[2], redm[3]));

    float s = 0.f;
    #pragma unroll
    for (int j = 0; j < 8; ++j)
        if (j < n) { v[j] = __expf(v[j] - mx); s += v[j]; }
    #pragma unroll
    for (int off = 32; off; off >>= 1) s += __shfl_xor(s, off);
    if ((tid & 63) == 0) reds[wid] = s;
    __syncthreads();
    s = reds[0] + reds[1] + reds[2] + reds[3];
    float inv = 1.f / s;
    #pragma unroll
    for (int j = 0; j < 8; ++j)
        if (j < n) p[tid + (j << 8)] = v[j] * inv;
}

// ---------------------------------------------------------------------------
// w0[b,q,k] = mean over 4 heads of probs (scale 0, L=2048). grid: 4*2048 rows.
// ---------------------------------------------------------------------------
__global__ __launch_bounds__(256) void w0_kernel(
    const float* __restrict__ probs, float* __restrict__ w0)
{
    const int L = 2048;
    int bq = blockIdx.x;
    int b = bq >> 11;
    int q = bq & 2047;
    const long hstride = (long)L * L;
    const float* p0 = probs + ((long)(b * 4) * L + q) * L;
    #pragma unroll
    for (int j = 0; j < 8; ++j) {
        int k = (j << 8) + threadIdx.x;
        float v = 0.25f * (p0[k] + p0[k + hstride] + p0[k + 2 * hstride] + p0[k + 3 * hstride]);
        w0[(long)bq * L + k] = v;
    }
}

// ---------------------------------------------------------------------------
// PV: O[bh, q, :64] = P[bh, q, :] @ V[bh, :, :64], written to o rows (b*L+q)*256, col h*64
// grid: (L/64, 1, 16)
// ---------------------------------------------------------------------------
__global__ __launch_bounds__(256) void pv_kernel(
    const float* __restrict__ probs, const float* __restrict__ qkv,
    float* __restrict__ o, int L)
{
    __shared__ float Ps[32][68];  // [k][q]
    __shared__ float Vs[32][68];  // [k][d]
    const int tid = threadIdx.x;
    const int tx = tid & 15, ty = tid >> 4;
    const int q0 = blockIdx.x * 64;
    const int bh = blockIdx.z;
    const int b = bh >> 2, h = bh & 3;
    const float* vbase = qkv + (long)(b * L) * 768 + 512 + h * 64;
    const float* pbase = probs + (long)bh * L * L;
    float acc[4][4] = {};

    for (int k0 = 0; k0 < L; k0 += 32) {
        #pragma unroll
        for (int it = 0; it < 8; ++it) {
            int f = tid + it * 256;
            int r = f >> 5, c = f & 31;      // r: q 0..63, c: k 0..31
            Ps[c][r] = pbase[(long)(q0 + r) * L + k0 + c];
        }
        #pragma unroll
        for (int it = 0; it < 8; ++it) {
            int f = tid + it * 256;
            int r = f >> 6, c = f & 63;      // r: k 0..31, c: d 0..63
            Vs[r][c] = vbase[(long)(k0 + r) * 768 + c];
        }
        __syncthreads();
        #pragma unroll
        for (int kk = 0; kk < 32; ++kk) {
            float4 a4 = *(const float4*)&Ps[kk][ty * 4];
            float4 w4 = *(const float4*)&Vs[kk][tx * 4];
            float a[4] = {a4.x, a4.y, a4.z, a4.w};
            float w[4] = {w4.x, w4.y, w4.z, w4.w};
            #pragma unroll
            for (int i = 0; i < 4; ++i)
                #pragma unroll
                for (int j = 0; j < 4; ++j)
                    acc[i][j] += a[i] * w[j];
        }
        __syncthreads();
    }

    #pragma unroll
    for (int i = 0; i < 4; ++i) {
        long row = (long)(b * L + q0 + ty * 4 + i);
        float4 o4 = {acc[i][0], acc[i][1], acc[i][2], acc[i][3]};
        *(float4*)&o[row * 256 + h * 64 + tx * 4] = o4;
    }
}

// ---------------------------------------------------------------------------
// Upsample scale i into concat cols [col0, col0+256).
// out[b, t, col0+c] = (1-a)*y[b,k,c] + a*y[b,k+1,c], k=t/s, a=(t%s)/s, y[L]=0.
// grid: 4*2048*256/256 blocks.
// ---------------------------------------------------------------------------
__global__ __launch_bounds__(256) void upsample_kernel(
    const float* __restrict__ y, float* __restrict__ ccat,
    int L, int s, int col0)
{
    int idx = blockIdx.x * 256 + threadIdx.x;
    int c = idx & 255;
    int t = (idx >> 8) & 2047;
    int b = idx >> 19;
    int k = t / s;
    int j = t - k * s;
    float a = (float)j / (float)s;
    float y0 = y[((long)(b * L + k)) * 256 + c];
    float y1 = (k + 1 < L) ? y[((long)(b * L + k + 1)) * 256 + c] : 0.f;
    ccat[((long)(b * 2048 + t)) * 1024 + col0 + c] = (1.f - a) * y0 + a * y1;
}

// ---------------------------------------------------------------------------
// LayerNorm in place on rows of 1024. grid: 8192 rows.
// ---------------------------------------------------------------------------
__global__ __launch_bounds__(256) void ln_kernel(
    float* __restrict__ z, const float* __restrict__ g, const float* __restrict__ bta)
{
    long row = blockIdx.x;
    float* p = z + row * 1024;
    const int tid = threadIdx.x;
    float v[4];
    float s = 0.f;
    #pragma unroll
    for (int j = 0; j < 4; ++j) { v[j] = p[tid + (j << 8)]; s += v[j]; }
    #pragma unroll
    for (int off = 32; off; off >>= 1) s += __shfl_xor(s, off);
    __shared__ float r0[4], r1[4];
    int wid = tid >> 6;
    if ((tid & 63) == 0) r0[wid] = s;
    __syncthreads();
    s = r0[0] + r0[1] + r0[2] + r0[3];
    float mu = s * (1.f / 1024.f);

    float q = 0.f;
    #pragma unroll
    for (int j = 0; j < 4; ++j) { float d = v[j] - mu; q += d * d; }
    #pragma unroll
    for (int off = 32; off; off >>= 1) q += __shfl_xor(q, off);
    if ((tid & 63) == 0) r1[wid] = q;
    __syncthreads();
    q = r1[0] + r1[1] + r1[2] + r1[3];
    float rstd = rsqrtf(q * (1.f / 1024.f) + 1e-5f);

    #pragma unroll
    for (int j = 0; j < 4; ++j) {
        int c = tid + (j << 8);
        p[c] = (v[j] - mu) * rstd * g[c] + bta[c];
    }
}

// ---------------------------------------------------------------------------
extern "C" void kernel_launch(void* const* d_in, const int* in_sizes, int n_in,
                              void* d_out, int out_size, void* d_ws, size_t ws_size,
                              hipStream_t stream)
{
    const float* x     = (const float*)d_in[0];
    const float* projW = (const float*)d_in[1];
    const float* projB = (const float*)d_in[2];
    const float* inW   = (const float*)d_in[3];
    const float* inB   = (const float*)d_in[4];
    const float* outW  = (const float*)d_in[5];
    const float* outB  = (const float*)d_in[6];
    const float* fusW  = (const float*)d_in[7];
    const float* fusB  = (const float*)d_in[8];
    const float* lnG   = (const float*)d_in[9];
    const float* lnB   = (const float*)d_in[10];

    float* fused = (float*)d_out;                  // 4*2048*1024 = 8388608
    float* w0    = fused + 8388608;                // 4*2048*2048 = 16777216

    // Workspace layout (floats). Total = 95,158,272 floats = 363 MiB.
    float* ws    = (float*)d_ws;
    float* xproj = ws;                  // 15360*256  (reused as attention output o)
    float* qkv   = xproj + 3932160;     // 15360*768
    float* probs = qkv + 11796480;      // 16*2048*2048 (scale-0 size, reused per scale)
    float* yall  = probs + 67108864;    // 15360*256
    float* ccat  = yall + 3932160;      // 8192*1024

    const int Ls[4] = {2048, 1024, 512, 256};
    const int ss[4] = {1, 2, 4, 8};
    const int Rr[4] = {0, 8192, 12288, 14336};  // row base per scale (B*L cumulative)

    // 1) Subsample + projection (subsample-first: row-wise op commutes with slicing)
    for (int i = 0; i < 4; ++i) {
        int L = Ls[i], M = 4 * L;
        gemm_bias_kernel<<<dim3(M / 64, 4), 256, 0, stream>>>(
            x, (long)2048 * 1024, L, ss[i] * 1024,
            projW + (long)i * 1024 * 256, 256,
            projB + i * 256,
            xproj + (long)Rr[i] * 256, 256, M, 256, 1024);
    }
    // 2) QKV for all scales (before xproj is recycled as o-buffer)
    for (int i = 0; i < 4; ++i) {
        int L = Ls[i], M = 4 * L;
        gemm_bias_kernel<<<dim3(M / 64, 12), 256, 0, stream>>>(
            xproj + (long)Rr[i] * 256, 0, M, 256,
            inW + (long)i * 256 * 768, 768,
            inB + i * 768,
            qkv + (long)Rr[i] * 768, 768, M, 768, 256);
    }
    // 3) Per-scale attention -> out-proj -> upsample
    for (int i = 0; i < 4; ++i) {
        int L = Ls[i], M = 4 * L;
        const float* qkv_i = qkv + (long)Rr[i] * 768;
        scores_kernel<<<dim3(L / 64, L / 64, 16), 256, 0, stream>>>(qkv_i, probs, L);
        softmax_kernel<<<16 * L, 256, 0, stream>>>(probs, L);
        if (i == 0)
            w0_kernel<<<4 * 2048, 256, 0, stream>>>(probs, w0);
        pv_kernel<<<dim3(L / 64, 1, 16), 256, 0, stream>>>(probs, qkv_i, xproj + (long)Rr[i] * 256, L);
        gemm_bias_kernel<<<dim3(M / 64, 4), 256, 0, stream>>>(
            xproj + (long)Rr[i] * 256, 0, M, 256,
            outW + (long)i * 256 * 256, 256,
            outB + i * 256,
            yall + (long)Rr[i] * 256, 256, M, 256, 256);
        upsample_kernel<<<(4 * 2048 * 256) / 256, 256, 0, stream>>>(
            yall + (long)Rr[i] * 256, ccat, L, ss[i], i * 256);
    }
    // 4) Fusion GEMM -> d_out, then LayerNorm in place
    gemm_bias_kernel<<<dim3(8192 / 64, 1024 / 64), 256, 0, stream>>>(
        ccat, 0, 8192, 1024, fusW, 1024, fusB, fused, 1024, 8192, 1024, 1024);
    ln_kernel<<<8192, 256, 0, stream>>>(fused, lnG, lnB);
}

// Round 2
// 747.996 us; speedup vs baseline: 2.4206x; 2.4206x over previous
//
#include <hip/hip_runtime.h>
#include <hip/hip_bf16.h>

// B=4, S=2048, D_MODEL=1024, NS=4 scales (1,2,4,8), E=256, H=4, DK=64
// out = [fused (4*2048*1024) fp32] ++ [w0 (4*2048*2048) fp32]

typedef short bh8 __attribute__((ext_vector_type(8)));   // 8 bf16 (4 VGPRs)
typedef float f32x4 __attribute__((ext_vector_type(4)));

__device__ __forceinline__ ushort f2b(float f) {
    __hip_bfloat16 h = __float2bfloat16(f);
    return *reinterpret_cast<ushort*>(&h);
}
__device__ __forceinline__ float b2f(ushort u) {
    __hip_bfloat16 h;
    *reinterpret_cast<ushort*>(&h) = u;
    return __bfloat162float(h);
}

// ---------------------------------------------------------------------------
// fp32 -> bf16 bulk convert (n multiple of 1024)
// ---------------------------------------------------------------------------
__global__ __launch_bounds__(256) void cvt_kernel(
    const float* __restrict__ s, ushort* __restrict__ d, long n)
{
    long i = ((long)blockIdx.x * 256 + threadIdx.x) * 4;
    if (i >= n) return;
    float4 v = *(const float4*)(s + i);
    ushort4 o;
    o.x = f2b(v.x); o.y = f2b(v.y); o.z = f2b(v.z); o.w = f2b(v.w);
    *(ushort4*)(d + i) = o;
}

// ---------------------------------------------------------------------------
// Weight transpose+convert: src fp32 [K][N] (batch z) -> dst bf16 [N][K]
// grid: (N/32, K/32, batch), block 256
// ---------------------------------------------------------------------------
__global__ __launch_bounds__(256) void wtrans_kernel(
    const float* __restrict__ src, ushort* __restrict__ dst, int K, int N)
{
    __shared__ float Ls[32][33];
    const int n0 = blockIdx.x * 32, k0 = blockIdx.y * 32;
    const float* s = src + (long)blockIdx.z * K * N;
    ushort* d = dst + (long)blockIdx.z * N * K;
    const int tid = threadIdx.x;
    #pragma unroll
    for (int it = 0; it < 4; ++it) {
        int f = tid + it * 256;
        int kc = f >> 5, rn = f & 31;
        Ls[kc][rn] = s[(long)(k0 + kc) * N + n0 + rn];
    }
    __syncthreads();
    #pragma unroll
    for (int it = 0; it < 2; ++it) {
        int f = tid + it * 256;
        int rn = f >> 4, kc2 = (f & 15) * 2;
        ushort2 o;
        o.x = f2b(Ls[kc2][rn]);
        o.y = f2b(Ls[kc2 + 1][rn]);
        *(ushort2*)&d[(long)(n0 + rn) * K + k0 + kc2] = o;
    }
}

// ---------------------------------------------------------------------------
// Generic bf16 MFMA GEMM.  C[z][m][n] = scale * sum_k A[z][m][k]*B[z][n][k] + bias[n]
// A row m addr: A + (z>>2)*a_zb + (z&3)*a_zh + (m/rpb)*a_bstride + (m%rpb)*a_rstride
// B row n addr: B + (z>>2)*b_zb + (z&3)*b_zh + n*b_rstride       (B pre-transposed [N][K])
// C elem addr : C + (z>>2)*c_zb + (z&3)*c_zh + m*c_rstride + n   (fp32 or bf16)
// WIDE: 128x128 tile; else 128x64. BK=64. 256 threads = 4 waves.
// M % 128 == 0, N % (WIDE?128:64) == 0, K % 64 == 0 required.
// ---------------------------------------------------------------------------
template<bool WIDE>
__global__ __launch_bounds__(256) void gemm_mfma(
    const ushort* __restrict__ A, long a_zb, long a_zh, int rpb, long a_bstride, int a_rstride,
    const ushort* __restrict__ B, long b_zb, long b_zh, int b_rstride,
    const float* __restrict__ bias,
    void* __restrict__ C, long c_zb, long c_zh, int c_rstride, int cfp32,
    float scale, int M, int N, int K)
{
    constexpr int BN  = WIDE ? 128 : 64;
    constexpr int NJ  = WIDE ? 4 : 2;
    constexpr int BIT = BN / 32;
    __shared__ ushort As[128][72];
    __shared__ ushort Bs[BN][72];

    const int tid = threadIdx.x;
    const int wave = tid >> 6, lane = tid & 63;
    const int lm = lane & 15, quad = lane >> 4;
    const int wm = (wave & 1) * 64;
    const int wn = (wave >> 1) * (WIDE ? 64 : 32);
    const int m0 = blockIdx.x * 128, n0 = blockIdx.y * BN;
    const int z = blockIdx.z;
    const long zo_a = (long)(z >> 2) * a_zb + (long)(z & 3) * a_zh;
    const long zo_b = (long)(z >> 2) * b_zb + (long)(z & 3) * b_zh;
    const long zo_c = (long)(z >> 2) * c_zb + (long)(z & 3) * c_zh;

    f32x4 acc[4][NJ];
    #pragma unroll
    for (int i = 0; i < 4; ++i)
        #pragma unroll
        for (int j = 0; j < NJ; ++j) {
            f32x4 zz = {0.f, 0.f, 0.f, 0.f};
            acc[i][j] = zz;
        }

    // staging assignment (constant over k-loop)
    const int r0 = tid >> 3;          // 0..31
    const int k8 = (tid & 7) * 8;     // 0..56
    const ushort* ap[4];
    #pragma unroll
    for (int it = 0; it < 4; ++it) {
        int m = m0 + r0 + it * 32;
        int bidx = m / rpb;
        int t = m - bidx * rpb;
        ap[it] = A + zo_a + (long)bidx * a_bstride + (long)t * a_rstride + k8;
    }
    const ushort* bp[BIT];
    #pragma unroll
    for (int it = 0; it < BIT; ++it) {
        int n = n0 + r0 + it * 32;
        bp[it] = B + zo_b + (long)n * b_rstride + k8;
    }

    for (int k0 = 0; k0 < K; k0 += 64) {
        #pragma unroll
        for (int it = 0; it < 4; ++it)
            *(bh8*)&As[r0 + it * 32][k8] = *(const bh8*)(ap[it] + k0);
        #pragma unroll
        for (int it = 0; it < BIT; ++it)
            *(bh8*)&Bs[r0 + it * 32][k8] = *(const bh8*)(bp[it] + k0);
        __syncthreads();
        #pragma unroll
        for (int ks = 0; ks < 2; ++ks) {
            bh8 af[4], bfv[NJ];
            #pragma unroll
            for (int i = 0; i < 4; ++i)
                af[i] = *(const bh8*)&As[wm + i * 16 + lm][ks * 32 + quad * 8];
            #pragma unroll
            for (int j = 0; j < NJ; ++j)
                bfv[j] = *(const bh8*)&Bs[wn + j * 16 + lm][ks * 32 + quad * 8];
            #pragma unroll
            for (int i = 0; i < 4; ++i)
                #pragma unroll
                for (int j = 0; j < NJ; ++j)
                    acc[i][j] = __builtin_amdgcn_mfma_f32_16x16x32_bf16(
                        af[i], bfv[j], acc[i][j], 0, 0, 0);
        }
        __syncthreads();
    }

    // epilogue: C/D layout col=lane&15, row=quad*4+reg
    float bv[NJ]; int cols[NJ];
    #pragma unroll
    for (int j = 0; j < NJ; ++j) {
        cols[j] = n0 + wn + j * 16 + lm;
        bv[j] = bias ? bias[cols[j]] : 0.f;
    }
    #pragma unroll
    for (int i = 0; i < 4; ++i) {
        int mb = m0 + wm + i * 16 + quad * 4;
        #pragma unroll
        for (int j = 0; j < NJ; ++j) {
            #pragma unroll
            for (int r = 0; r < 4; ++r) {
                float v = acc[i][j][r] * scale + bv[j];
                long off = zo_c + (long)(mb + r) * c_rstride + cols[j];
                if (cfp32) ((float*)C)[off] = v;
                else       ((ushort*)C)[off] = f2b(v);
            }
        }
    }
}

// ---------------------------------------------------------------------------
// V transpose: qkv bf16 rows [(b*L+k)][768] col 512+h*64+d -> vT[z][d][k]
// grid: (L/64, 1, 16), block 256
// ---------------------------------------------------------------------------
__global__ __launch_bounds__(256) void vtrans_kernel(
    const ushort* __restrict__ qkv, ushort* __restrict__ vT, int L)
{
    __shared__ ushort Ls[64][72];
    const int z = blockIdx.z, b = z >> 2, h = z & 3;
    const int k0 = blockIdx.x * 64;
    const ushort* src = qkv + (long)b * L * 768 + 512 + h * 64;
    const int tid = threadIdx.x;
    const int kk = tid >> 3, d8 = (tid & 7) * 8;
    #pragma unroll
    for (int it = 0; it < 2; ++it) {
        int k = kk + it * 32;
        bh8 v = *(const bh8*)(src + (long)(k0 + k) * 768 + d8);
        ushort tmp[8];
        *(bh8*)tmp = v;
        #pragma unroll
        for (int j = 0; j < 8; ++j) Ls[d8 + j][k] = tmp[j];
    }
    __syncthreads();
    ushort* dst = vT + (long)z * 64 * L;
    #pragma unroll
    for (int it = 0; it < 2; ++it) {
        int d = kk + it * 32;
        *(bh8*)(dst + (long)d * L + k0 + d8) = *(const bh8*)&Ls[d][d8];
    }
}

// ---------------------------------------------------------------------------
// Row softmax: reads fp32 logits row, writes bf16 probs IN PLACE
// (first L ushorts of the row's 4L bytes). grid: 16*L rows.
// ---------------------------------------------------------------------------
__global__ __launch_bounds__(256) void softmax_kernel(float* __restrict__ logits, int L)
{
    long row = blockIdx.x;
    float* p = logits + row * (long)L;
    ushort* pb = (ushort*)p;
    const int tid = threadIdx.x;
    const int n = L >> 8;
    float v[8];
    float mx = -1e30f;
    #pragma unroll
    for (int j = 0; j < 8; ++j)
        if (j < n) { v[j] = p[tid + (j << 8)]; mx = fmaxf(mx, v[j]); }
    #pragma unroll
    for (int off = 32; off; off >>= 1) mx = fmaxf(mx, __shfl_xor(mx, off));
    __shared__ float redm[4], reds[4];
    int wid = tid >> 6;
    if ((tid & 63) == 0) redm[wid] = mx;
    __syncthreads();
    mx = fmaxf(fmaxf(redm[0], redm[1]), fmaxf(redm[2], redm[3]));
    float s = 0.f;
    #pragma unroll
    for (int j = 0; j < 8; ++j)
        if (j < n) { v[j] = __expf(v[j] - mx); s += v[j]; }
    #pragma unroll
    for (int off = 32; off; off >>= 1) s += __shfl_xor(s, off);
    if ((tid & 63) == 0) reds[wid] = s;
    __syncthreads();
    s = reds[0] + reds[1] + reds[2] + reds[3];
    float inv = 1.f / s;
    #pragma unroll
    for (int j = 0; j < 8; ++j)
        if (j < n) pb[tid + (j << 8)] = f2b(v[j] * inv);
}

// ---------------------------------------------------------------------------
// w0[b,q,:] = mean over 4 heads of bf16 probs (scale 0, L=2048, row stride 4096 ushorts)
// grid: 4*2048 rows.
// ---------------------------------------------------------------------------
__global__ __launch_bounds__(256) void w0_kernel(
    const ushort* __restrict__ probs, float* __restrict__ out_w0)
{
    int bq = blockIdx.x;
    int b = bq >> 11, q = bq & 2047;
    const long r0off = ((long)(b * 4) * 2048 + q) * 4096;
    const long hs = (long)2048 * 4096;
    #pragma unroll
    for (int it = 0; it < 2; ++it) {
        int k4 = (threadIdx.x + it * 256) * 4;
        ushort4 a0 = *(const ushort4*)(probs + r0off + k4);
        ushort4 a1 = *(const ushort4*)(probs + r0off + hs + k4);
        ushort4 a2 = *(const ushort4*)(probs + r0off + 2 * hs + k4);
        ushort4 a3 = *(const ushort4*)(probs + r0off + 3 * hs + k4);
        float4 o;
        o.x = 0.25f * (b2f(a0.x) + b2f(a1.x) + b2f(a2.x) + b2f(a3.x));
        o.y = 0.25f * (b2f(a0.y) + b2f(a1.y) + b2f(a2.y) + b2f(a3.y));
        o.z = 0.25f * (b2f(a0.z) + b2f(a1.z) + b2f(a2.z) + b2f(a3.z));
        o.w = 0.25f * (b2f(a0.w) + b2f(a1.w) + b2f(a2.w) + b2f(a3.w));
        *(float4*)&out_w0[(long)bq * 2048 + k4] = o;
    }
}

// ---------------------------------------------------------------------------
// Upsample scale into concat cols [col0, col0+256). bf16 in/out. grid 2048.
// ---------------------------------------------------------------------------
__global__ __launch_bounds__(256) void upsample_kernel(
    const ushort* __restrict__ y, ushort* __restrict__ ccat, int L, int s, int col0)
{
    int idx = blockIdx.x * 256 + threadIdx.x;  // 524288
    int c4 = (idx & 63) * 4;
    int t = (idx >> 6) & 2047;
    int b = idx >> 17;
    int k = t / s, j = t - k * s;
    float a = (float)j / (float)s;
    const ushort* y0p = y + ((long)(b * L + k)) * 256 + c4;
    ushort4 y0 = *(const ushort4*)y0p;
    ushort4 y1 = {0, 0, 0, 0};
    if (k + 1 < L) y1 = *(const ushort4*)(y0p + 256);
    ushort4 o;
    o.x = f2b((1.f - a) * b2f(y0.x) + a * b2f(y1.x));
    o.y = f2b((1.f - a) * b2f(y0.y) + a * b2f(y1.y));
    o.z = f2b((1.f - a) * b2f(y0.z) + a * b2f(y1.z));
    o.w = f2b((1.f - a) * b2f(y0.w) + a * b2f(y1.w));
    *(ushort4*)&ccat[((long)(b * 2048 + t)) * 1024 + col0 + c4] = o;
}

// ---------------------------------------------------------------------------
// LayerNorm in place on fp32 rows of 1024. grid: 8192 rows.
// ---------------------------------------------------------------------------
__global__ __launch_bounds__(256) void ln_kernel(
    float* __restrict__ zbuf, const float* __restrict__ g, const float* __restrict__ bta)
{
    long row = blockIdx.x;
    float* p = zbuf + row * 1024;
    const int tid = threadIdx.x;
    float v[4];
    float s = 0.f;
    #pragma unroll
    for (int j = 0; j < 4; ++j) { v[j] = p[tid + (j << 8)]; s += v[j]; }
    #pragma unroll
    for (int off = 32; off; off >>= 1) s += __shfl_xor(s, off);
    __shared__ float r0[4], r1[4];
    int wid = tid >> 6;
    if ((tid & 63) == 0) r0[wid] = s;
    __syncthreads();
    s = r0[0] + r0[1] + r0[2] + r0[3];
    float mu = s * (1.f / 1024.f);
    float q = 0.f;
    #pragma unroll
    for (int j = 0; j < 4; ++j) { float d = v[j] - mu; q += d * d; }
    #pragma unroll
    for (int off = 32; off; off >>= 1) q += __shfl_xor(q, off);
    if ((tid & 63) == 0) r1[wid] = q;
    __syncthreads();
    q = r1[0] + r1[1] + r1[2] + r1[3];
    float rstd = rsqrtf(q * (1.f / 1024.f) + 1e-5f);
    #pragma unroll
    for (int j = 0; j < 4; ++j) {
        int c = tid + (j << 8);
        p[c] = (v[j] - mu) * rstd * g[c] + bta[c];
    }
}

// ---------------------------------------------------------------------------
extern "C" void kernel_launch(void* const* d_in, const int* in_sizes, int n_in,
                              void* d_out, int out_size, void* d_ws, size_t ws_size,
                              hipStream_t stream)
{
    const float* x     = (const float*)d_in[0];
    const float* projW = (const float*)d_in[1];
    const float* projB = (const float*)d_in[2];
    const float* inW   = (const float*)d_in[3];
    const float* inB   = (const float*)d_in[4];
    const float* outW  = (const float*)d_in[5];
    const float* outB  = (const float*)d_in[6];
    const float* fusW  = (const float*)d_in[7];
    const float* fusB  = (const float*)d_in[8];
    const float* lnG   = (const float*)d_in[9];
    const float* lnB   = (const float*)d_in[10];

    float* fused  = (float*)d_out;
    float* out_w0 = fused + 8388608;

    // workspace layout (bytes; total ~343 MB)
    char* w = (char*)d_ws;
    ushort* xb     = (ushort*)w; w += 16777216;   // x bf16 [4*2048][1024]
    ushort* pT     = (ushort*)w; w += 2097152;    // projW^T bf16 [4][256][1024]
    ushort* iT     = (ushort*)w; w += 1572864;    // inW^T   bf16 [4][768][256]
    ushort* oT     = (ushort*)w; w += 524288;     // outW^T  bf16 [4][256][256]
    ushort* fT     = (ushort*)w; w += 2097152;    // fusW^T  bf16 [1024][1024]
    ushort* xprojb = (ushort*)w; w += 7864320;    // [15360][256]
    ushort* qkvb   = (ushort*)w; w += 23592960;   // [15360][768]
    ushort* ob     = (ushort*)w; w += 7864320;    // attn out [15360][256]
    ushort* yallb  = (ushort*)w; w += 7864320;    // out-proj [15360][256]
    ushort* ccatb  = (ushort*)w; w += 16777216;   // concat   [8192][1024]
    ushort* vTb    = (ushort*)w; w += 4194304;    // V^T [16][64][Lmax]
    float*  logits = (float*)w;  w += 268435456;  // [16][L][L] fp32 / bf16 probs in place

    const int Ls_[4] = {2048, 1024, 512, 256};
    const int ss_[4] = {1, 2, 4, 8};
    const int Rr_[4] = {0, 8192, 12288, 14336};
    const int BIG = 1 << 30;

    // 0) converts + weight transposes
    cvt_kernel<<<8192, 256, 0, stream>>>(x, xb, 8388608);
    wtrans_kernel<<<dim3(8, 32, 4), 256, 0, stream>>>(projW, pT, 1024, 256);
    wtrans_kernel<<<dim3(24, 8, 4), 256, 0, stream>>>(inW, iT, 256, 768);
    wtrans_kernel<<<dim3(8, 8, 4), 256, 0, stream>>>(outW, oT, 256, 256);
    wtrans_kernel<<<dim3(32, 32, 1), 256, 0, stream>>>(fusW, fT, 1024, 1024);

    // 1) proj (subsample-first gather)
    for (int i = 0; i < 4; ++i) {
        int L = Ls_[i], M = 4 * L;
        gemm_mfma<true><<<dim3(M / 128, 2, 1), 256, 0, stream>>>(
            xb, 0, 0, L, (long)2097152, ss_[i] * 1024,
            pT + (long)i * 262144, 0, 0, 1024,
            projB + i * 256,
            xprojb + (long)Rr_[i] * 256, 0, 0, 256, 0, 1.f, M, 256, 1024);
    }
    // 2) QKV
    for (int i = 0; i < 4; ++i) {
        int L = Ls_[i], M = 4 * L;
        gemm_mfma<true><<<dim3(M / 128, 6, 1), 256, 0, stream>>>(
            xprojb + (long)Rr_[i] * 256, 0, 0, BIG, 0, 256,
            iT + (long)i * 196608, 0, 0, 256,
            inB + i * 768,
            qkvb + (long)Rr_[i] * 768, 0, 0, 768, 0, 1.f, M, 768, 256);
    }
    // 3) per-scale attention
    for (int i = 0; i < 4; ++i) {
        int L = Ls_[i], M = 4 * L;
        const ushort* qkv_i = qkvb + (long)Rr_[i] * 768;
        // scores -> fp32 logits
        gemm_mfma<true><<<dim3(L / 128, L / 128, 16), 256, 0, stream>>>(
            qkv_i, (long)L * 768, 64, BIG, 0, 768,
            qkv_i + 256, (long)L * 768, 64, 768,
            nullptr,
            logits, (long)4 * L * L, (long)L * L, L, 1, 0.125f, L, L, 64);
        softmax_kernel<<<16 * L, 256, 0, stream>>>(logits, L);
        if (i == 0)
            w0_kernel<<<8192, 256, 0, stream>>>((const ushort*)logits, out_w0);
        vtrans_kernel<<<dim3(L / 64, 1, 16), 256, 0, stream>>>(qkv_i, vTb, L);
        // PV (A = bf16 probs in-place, row stride 2L ushorts)
        gemm_mfma<false><<<dim3(L / 128, 1, 16), 256, 0, stream>>>(
            (const ushort*)logits, (long)8 * L * L, (long)2 * L * L, BIG, 0, 2 * L,
            vTb, (long)4 * 64 * L, (long)64 * L, L,
            nullptr,
            ob + (long)Rr_[i] * 256, (long)L * 256, 64, 256, 0, 1.f, L, 64, L);
        // out-proj
        gemm_mfma<true><<<dim3(M / 128, 2, 1), 256, 0, stream>>>(
            ob + (long)Rr_[i] * 256, 0, 0, BIG, 0, 256,
            oT + (long)i * 65536, 0, 0, 256,
            outB + i * 256,
            yallb + (long)Rr_[i] * 256, 0, 0, 256, 0, 1.f, M, 256, 256);
        upsample_kernel<<<2048, 256, 0, stream>>>(
            yallb + (long)Rr_[i] * 256, ccatb, L, ss_[i], i * 256);
    }
    // 4) fusion GEMM -> fp32 d_out, then LN
    gemm_mfma<true><<<dim3(64, 8, 1), 256, 0, stream>>>(
        ccatb, 0, 0, BIG, 0, 1024,
        fT, 0, 0, 1024,
        fusB,
        fused, 0, 0, 1024, 1, 1.f, 8192, 1024, 1024);
    ln_kernel<<<8192, 256, 0, stream>>>(fused, lnG, lnB);
}

// Round 3
// 532.580 us; speedup vs baseline: 3.3996x; 1.4045x over previous
//
#include <hip/hip_runtime.h>
#include <hip/hip_bf16.h>

// B=4, S=2048, D_MODEL=1024, NS=4 scales (1,2,4,8), E=256, H=4, DK=64
// out = [fused (4*2048*1024) fp32] ++ [w0 (4*2048*2048) fp32]

typedef short bh8 __attribute__((ext_vector_type(8)));   // 8 bf16 (4 VGPRs)
typedef float f32x4 __attribute__((ext_vector_type(4)));

__device__ __forceinline__ ushort f2b(float f) {
    __hip_bfloat16 h = __float2bfloat16(f);
    return *reinterpret_cast<ushort*>(&h);
}
__device__ __forceinline__ float b2f(ushort u) {
    __hip_bfloat16 h;
    *reinterpret_cast<ushort*>(&h) = u;
    return __bfloat162float(h);
}

// ---------------------------------------------------------------------------
// fp32 -> bf16 bulk convert
// ---------------------------------------------------------------------------
__global__ __launch_bounds__(256) void cvt_kernel(
    const float* __restrict__ s, ushort* __restrict__ d, long n)
{
    long i = ((long)blockIdx.x * 256 + threadIdx.x) * 4;
    if (i >= n) return;
    float4 v = *(const float4*)(s + i);
    ushort4 o;
    o.x = f2b(v.x); o.y = f2b(v.y); o.z = f2b(v.z); o.w = f2b(v.w);
    *(ushort4*)(d + i) = o;
}

// ---------------------------------------------------------------------------
// Weight transpose+convert: src fp32 [K][N] (batch z) -> dst bf16 [N][K]
// ---------------------------------------------------------------------------
__global__ __launch_bounds__(256) void wtrans_kernel(
    const float* __restrict__ src, ushort* __restrict__ dst, int K, int N)
{
    __shared__ float Ls[32][33];
    const int n0 = blockIdx.x * 32, k0 = blockIdx.y * 32;
    const float* s = src + (long)blockIdx.z * K * N;
    ushort* d = dst + (long)blockIdx.z * N * K;
    const int tid = threadIdx.x;
    #pragma unroll
    for (int it = 0; it < 4; ++it) {
        int f = tid + it * 256;
        int kc = f >> 5, rn = f & 31;
        Ls[kc][rn] = s[(long)(k0 + kc) * N + n0 + rn];
    }
    __syncthreads();
    #pragma unroll
    for (int it = 0; it < 2; ++it) {
        int f = tid + it * 256;
        int rn = f >> 4, kc2 = (f & 15) * 2;
        ushort2 o;
        o.x = f2b(Ls[kc2][rn]);
        o.y = f2b(Ls[kc2 + 1][rn]);
        *(ushort2*)&d[(long)(n0 + rn) * K + k0 + kc2] = o;
    }
}

// ---------------------------------------------------------------------------
// Generic bf16 MFMA GEMM (see round 2). C = scale*A@B^T + bias.
// ---------------------------------------------------------------------------
template<bool WIDE>
__global__ __launch_bounds__(256) void gemm_mfma(
    const ushort* __restrict__ A, long a_zb, long a_zh, int rpb, long a_bstride, int a_rstride,
    const ushort* __restrict__ B, long b_zb, long b_zh, int b_rstride,
    const float* __restrict__ bias,
    void* __restrict__ C, long c_zb, long c_zh, int c_rstride, int cfp32,
    float scale, int M, int N, int K)
{
    constexpr int BN  = WIDE ? 128 : 64;
    constexpr int NJ  = WIDE ? 4 : 2;
    constexpr int BIT = BN / 32;
    __shared__ ushort As[128][72];
    __shared__ ushort Bs[BN][72];

    const int tid = threadIdx.x;
    const int wave = tid >> 6, lane = tid & 63;
    const int lm = lane & 15, quad = lane >> 4;
    const int wm = (wave & 1) * 64;
    const int wn = (wave >> 1) * (WIDE ? 64 : 32);
    const int m0 = blockIdx.x * 128, n0 = blockIdx.y * BN;
    const int z = blockIdx.z;
    const long zo_a = (long)(z >> 2) * a_zb + (long)(z & 3) * a_zh;
    const long zo_b = (long)(z >> 2) * b_zb + (long)(z & 3) * b_zh;
    const long zo_c = (long)(z >> 2) * c_zb + (long)(z & 3) * c_zh;

    f32x4 acc[4][NJ];
    #pragma unroll
    for (int i = 0; i < 4; ++i)
        #pragma unroll
        for (int j = 0; j < NJ; ++j) {
            f32x4 zz = {0.f, 0.f, 0.f, 0.f};
            acc[i][j] = zz;
        }

    const int r0 = tid >> 3;
    const int k8 = (tid & 7) * 8;
    const ushort* ap[4];
    #pragma unroll
    for (int it = 0; it < 4; ++it) {
        int m = m0 + r0 + it * 32;
        int bidx = m / rpb;
        int t = m - bidx * rpb;
        ap[it] = A + zo_a + (long)bidx * a_bstride + (long)t * a_rstride + k8;
    }
    const ushort* bp[BIT];
    #pragma unroll
    for (int it = 0; it < BIT; ++it) {
        int n = n0 + r0 + it * 32;
        bp[it] = B + zo_b + (long)n * b_rstride + k8;
    }

    for (int k0 = 0; k0 < K; k0 += 64) {
        #pragma unroll
        for (int it = 0; it < 4; ++it)
            *(bh8*)&As[r0 + it * 32][k8] = *(const bh8*)(ap[it] + k0);
        #pragma unroll
        for (int it = 0; it < BIT; ++it)
            *(bh8*)&Bs[r0 + it * 32][k8] = *(const bh8*)(bp[it] + k0);
        __syncthreads();
        #pragma unroll
        for (int ks = 0; ks < 2; ++ks) {
            bh8 af[4], bfv[NJ];
            #pragma unroll
            for (int i = 0; i < 4; ++i)
                af[i] = *(const bh8*)&As[wm + i * 16 + lm][ks * 32 + quad * 8];
            #pragma unroll
            for (int j = 0; j < NJ; ++j)
                bfv[j] = *(const bh8*)&Bs[wn + j * 16 + lm][ks * 32 + quad * 8];
            #pragma unroll
            for (int i = 0; i < 4; ++i)
                #pragma unroll
                for (int j = 0; j < NJ; ++j)
                    acc[i][j] = __builtin_amdgcn_mfma_f32_16x16x32_bf16(
                        af[i], bfv[j], acc[i][j], 0, 0, 0);
        }
        __syncthreads();
    }

    float bv[NJ]; int cols[NJ];
    #pragma unroll
    for (int j = 0; j < NJ; ++j) {
        cols[j] = n0 + wn + j * 16 + lm;
        bv[j] = bias ? bias[cols[j]] : 0.f;
    }
    #pragma unroll
    for (int i = 0; i < 4; ++i) {
        int mb = m0 + wm + i * 16 + quad * 4;
        #pragma unroll
        for (int j = 0; j < NJ; ++j) {
            #pragma unroll
            for (int r = 0; r < 4; ++r) {
                float v = acc[i][j][r] * scale + bv[j];
                long off = zo_c + (long)(mb + r) * c_rstride + cols[j];
                if (cfp32) ((float*)C)[off] = v;
                else       ((ushort*)C)[off] = f2b(v);
            }
        }
    }
}

// ---------------------------------------------------------------------------
// V transpose: qkv bf16 rows [(b*L+k)][768] col 512+h*64+d -> vT[z][d][k]
// ---------------------------------------------------------------------------
__global__ __launch_bounds__(256) void vtrans_kernel(
    const ushort* __restrict__ qkv, ushort* __restrict__ vT, int L)
{
    __shared__ ushort Ls[64][72];
    const int z = blockIdx.z, b = z >> 2, h = z & 3;
    const int k0 = blockIdx.x * 64;
    const ushort* src = qkv + (long)b * L * 768 + 512 + h * 64;
    const int tid = threadIdx.x;
    const int kk = tid >> 3, d8 = (tid & 7) * 8;
    #pragma unroll
    for (int it = 0; it < 2; ++it) {
        int k = kk + it * 32;
        bh8 v = *(const bh8*)(src + (long)(k0 + k) * 768 + d8);
        ushort tmp[8];
        *(bh8*)tmp = v;
        #pragma unroll
        for (int j = 0; j < 8; ++j) Ls[d8 + j][k] = tmp[j];
    }
    __syncthreads();
    ushort* dst = vT + (long)z * 64 * L;
    #pragma unroll
    for (int it = 0; it < 2; ++it) {
        int d = kk + it * 32;
        *(bh8*)(dst + (long)d * L + k0 + d8) = *(const bh8*)&Ls[d][d8];
    }
}

// ---------------------------------------------------------------------------
// Fused flash attention per (bh, 128-q-tile). BQ=128, BK=128, D=64.
// 4 waves, each owns 32 q-rows (2 MFMA m-tiles). Online softmax in regs.
// WML: also store per-row scaled max (0.125*m) and 1/l for scale-0 w0 recompute.
// ---------------------------------------------------------------------------
template<bool WML>
__global__ __launch_bounds__(256, 2) void attn_flash(
    const ushort* __restrict__ qkv, const ushort* __restrict__ vT,
    ushort* __restrict__ o, float* __restrict__ msc, float* __restrict__ invl,
    int L)
{
    __shared__ ushort Ks[128 * 72];   // [k][d] stride 72
    __shared__ ushort Vs[64 * 136];   // [d][k] stride 136
    __shared__ ushort Ps[128 * 136];  // [q][k] stride 136 (also Q staging)

    const int tid = threadIdx.x;
    const int wave = tid >> 6, lane = tid & 63;
    const int lm = lane & 15, quad = lane >> 4;
    const int wm = wave * 32;
    const int q0 = blockIdx.x * 128;
    const int z = blockIdx.z;
    const int b = z >> 2, h = z & 3;
    const ushort* qbase = qkv + (long)b * L * 768 + h * 64;
    const ushort* kbase = qbase + 256;
    const ushort* vbase = vT + (long)z * 64 * L;
    const int r0 = tid >> 3, k8 = (tid & 7) * 8;
    const int vd0 = tid >> 4, vc8 = (tid & 15) * 8;

    // stage Q tile into Ps region (stride 136), pull A-frags to regs
    #pragma unroll
    for (int it = 0; it < 4; ++it) {
        int r = r0 + it * 32;
        *(bh8*)&Ps[r * 136 + k8] = *(const bh8*)(qbase + (long)(q0 + r) * 768 + k8);
    }
    __syncthreads();
    bh8 qf[2][2];
    #pragma unroll
    for (int mi = 0; mi < 2; ++mi)
        #pragma unroll
        for (int ks = 0; ks < 2; ++ks)
            qf[mi][ks] = *(const bh8*)&Ps[(wm + mi * 16 + lm) * 136 + ks * 32 + quad * 8];

    f32x4 oc[2][4];
    #pragma unroll
    for (int mi = 0; mi < 2; ++mi)
        #pragma unroll
        for (int nj = 0; nj < 4; ++nj) {
            f32x4 zz = {0.f, 0.f, 0.f, 0.f};
            oc[mi][nj] = zz;
        }
    float m_run[2][4], l_run[2][4];
    #pragma unroll
    for (int mi = 0; mi < 2; ++mi)
        #pragma unroll
        for (int rr = 0; rr < 4; ++rr) { m_run[mi][rr] = -3.0e38f; l_run[mi][rr] = 0.f; }

    for (int k0 = 0; k0 < L; k0 += 128) {
        // stage K tile [128][64] and V^T tile [64][128]
        #pragma unroll
        for (int it = 0; it < 4; ++it) {
            int r = r0 + it * 32;
            *(bh8*)&Ks[r * 72 + k8] = *(const bh8*)(kbase + (long)(k0 + r) * 768 + k8);
        }
        #pragma unroll
        for (int it = 0; it < 4; ++it) {
            int d = vd0 + it * 16;
            *(bh8*)&Vs[d * 136 + vc8] = *(const bh8*)(vbase + (long)d * L + k0 + vc8);
        }
        __syncthreads();

        // S = Q K^T  (raw, scale folded into exp)
        f32x4 sc[2][8];
        #pragma unroll
        for (int mi = 0; mi < 2; ++mi)
            #pragma unroll
            for (int nj = 0; nj < 8; ++nj) {
                f32x4 zz = {0.f, 0.f, 0.f, 0.f};
                sc[mi][nj] = zz;
            }
        #pragma unroll
        for (int ks = 0; ks < 2; ++ks)
            #pragma unroll
            for (int nj = 0; nj < 8; ++nj) {
                bh8 kf = *(const bh8*)&Ks[(nj * 16 + lm) * 72 + ks * 32 + quad * 8];
                #pragma unroll
                for (int mi = 0; mi < 2; ++mi)
                    sc[mi][nj] = __builtin_amdgcn_mfma_f32_16x16x32_bf16(
                        qf[mi][ks], kf, sc[mi][nj], 0, 0, 0);
            }

        // online softmax + P -> Ps (bf16, A-layout source)
        #pragma unroll
        for (int mi = 0; mi < 2; ++mi)
            #pragma unroll
            for (int rr = 0; rr < 4; ++rr) {
                float t = sc[mi][0][rr];
                #pragma unroll
                for (int nj = 1; nj < 8; ++nj) t = fmaxf(t, sc[mi][nj][rr]);
                t = fmaxf(t, __shfl_xor(t, 1));
                t = fmaxf(t, __shfl_xor(t, 2));
                t = fmaxf(t, __shfl_xor(t, 4));
                t = fmaxf(t, __shfl_xor(t, 8));
                float mo = m_run[mi][rr];
                float mn = fmaxf(mo, t);
                float alpha = __expf(0.125f * (mo - mn));
                m_run[mi][rr] = mn;
                float rs = 0.f;
                int prow = (wm + mi * 16 + quad * 4 + rr) * 136;
                #pragma unroll
                for (int nj = 0; nj < 8; ++nj) {
                    float p = __expf(0.125f * (sc[mi][nj][rr] - mn));
                    rs += p;
                    Ps[prow + nj * 16 + lm] = f2b(p);
                }
                rs += __shfl_xor(rs, 1);
                rs += __shfl_xor(rs, 2);
                rs += __shfl_xor(rs, 4);
                rs += __shfl_xor(rs, 8);
                l_run[mi][rr] = l_run[mi][rr] * alpha + rs;
                #pragma unroll
                for (int nj = 0; nj < 4; ++nj) oc[mi][nj][rr] *= alpha;
            }

        // O += P V  (P rows are wave-private; per-wave DS ordering covers RAW)
        #pragma unroll
        for (int kst = 0; kst < 4; ++kst) {
            bh8 pf[2];
            #pragma unroll
            for (int mi = 0; mi < 2; ++mi)
                pf[mi] = *(const bh8*)&Ps[(wm + mi * 16 + lm) * 136 + kst * 32 + quad * 8];
            #pragma unroll
            for (int nj = 0; nj < 4; ++nj) {
                bh8 vf = *(const bh8*)&Vs[(nj * 16 + lm) * 136 + kst * 32 + quad * 8];
                #pragma unroll
                for (int mi = 0; mi < 2; ++mi)
                    oc[mi][nj] = __builtin_amdgcn_mfma_f32_16x16x32_bf16(
                        pf[mi], vf, oc[mi][nj], 0, 0, 0);
            }
        }
        __syncthreads();
    }

    // epilogue
    #pragma unroll
    for (int mi = 0; mi < 2; ++mi)
        #pragma unroll
        for (int rr = 0; rr < 4; ++rr) {
            float il = 1.f / l_run[mi][rr];
            int q = q0 + wm + mi * 16 + quad * 4 + rr;
            if (WML && lm == 0) {
                msc[(long)z * L + q] = 0.125f * m_run[mi][rr];
                invl[(long)z * L + q] = il;
            }
            long rbase = ((long)(b * L + q)) * 256 + h * 64;
            #pragma unroll
            for (int nj = 0; nj < 4; ++nj)
                o[rbase + nj * 16 + lm] = f2b(oc[mi][nj][rr] * il);
        }
}

// ---------------------------------------------------------------------------
// w0 = mean over heads of probs, recomputed from Q,K + saved (0.125*m, 1/l).
// grid (16 q-tiles, 16 k-tiles, 4 b). Coalesced fp32 output via LDS staging.
// ---------------------------------------------------------------------------
__global__ __launch_bounds__(256, 2) void w0_recompute(
    const ushort* __restrict__ qkv,
    const float* __restrict__ msc, const float* __restrict__ invl,
    float* __restrict__ w0)
{
    const int L = 2048;
    __shared__ ushort Qs[128 * 72];
    __shared__ ushort Ks[128 * 72];
    __shared__ ushort Ws[128 * 136];

    const int tid = threadIdx.x;
    const int wave = tid >> 6, lane = tid & 63;
    const int lm = lane & 15, quad = lane >> 4;
    const int wm = wave * 32;
    const int q0 = blockIdx.x * 128, k0 = blockIdx.y * 128;
    const int b = blockIdx.z;
    const int r0 = tid >> 3, k8 = (tid & 7) * 8;

    f32x4 acc[2][8];
    #pragma unroll
    for (int mi = 0; mi < 2; ++mi)
        #pragma unroll
        for (int nj = 0; nj < 8; ++nj) {
            f32x4 zz = {0.f, 0.f, 0.f, 0.f};
            acc[mi][nj] = zz;
        }

    for (int h = 0; h < 4; ++h) {
        const ushort* qb = qkv + (long)b * L * 768 + h * 64;
        const ushort* kb = qb + 256;
        #pragma unroll
        for (int it = 0; it < 4; ++it) {
            int r = r0 + it * 32;
            *(bh8*)&Qs[r * 72 + k8] = *(const bh8*)(qb + (long)(q0 + r) * 768 + k8);
            *(bh8*)&Ks[r * 72 + k8] = *(const bh8*)(kb + (long)(k0 + r) * 768 + k8);
        }
        __syncthreads();
        bh8 qf[2][2];
        #pragma unroll
        for (int mi = 0; mi < 2; ++mi)
            #pragma unroll
            for (int ks = 0; ks < 2; ++ks)
                qf[mi][ks] = *(const bh8*)&Qs[(wm + mi * 16 + lm) * 72 + ks * 32 + quad * 8];
        f32x4 sc[2][8];
        #pragma unroll
        for (int mi = 0; mi < 2; ++mi)
            #pragma unroll
            for (int nj = 0; nj < 8; ++nj) {
                f32x4 zz = {0.f, 0.f, 0.f, 0.f};
                sc[mi][nj] = zz;
            }
        #pragma unroll
        for (int ks = 0; ks < 2; ++ks)
            #pragma unroll
            for (int nj = 0; nj < 8; ++nj) {
                bh8 kf = *(const bh8*)&Ks[(nj * 16 + lm) * 72 + ks * 32 + quad * 8];
                #pragma unroll
                for (int mi = 0; mi < 2; ++mi)
                    sc[mi][nj] = __builtin_amdgcn_mfma_f32_16x16x32_bf16(
                        qf[mi][ks], kf, sc[mi][nj], 0, 0, 0);
            }
        const float* mz = msc + (long)(b * 4 + h) * L;
        const float* iz = invl + (long)(b * 4 + h) * L;
        #pragma unroll
        for (int mi = 0; mi < 2; ++mi)
            #pragma unroll
            for (int rr = 0; rr < 4; ++rr) {
                int q = q0 + wm + mi * 16 + quad * 4 + rr;
                float mv = mz[q], iv = iz[q];
                #pragma unroll
                for (int nj = 0; nj < 8; ++nj)
                    acc[mi][nj][rr] += __expf(0.125f * sc[mi][nj][rr] - mv) * iv;
            }
        __syncthreads();
    }

    // stage tile (bf16) for coalesced fp32 store
    #pragma unroll
    for (int mi = 0; mi < 2; ++mi)
        #pragma unroll
        for (int rr = 0; rr < 4; ++rr) {
            int prow = (wm + mi * 16 + quad * 4 + rr) * 136;
            #pragma unroll
            for (int nj = 0; nj < 8; ++nj)
                Ws[prow + nj * 16 + lm] = f2b(0.25f * acc[mi][nj][rr]);
        }
    __syncthreads();
    #pragma unroll
    for (int it = 0; it < 8; ++it) {
        int idx = tid + it * 256;
        int row = idx >> 4, c8 = (idx & 15) * 8;
        ushort tmp[8];
        *(bh8*)tmp = *(const bh8*)&Ws[row * 136 + c8];
        long base = ((long)b * 2048 + q0 + row) * 2048 + k0 + c8;
        float4 f0, f1;
        f0.x = b2f(tmp[0]); f0.y = b2f(tmp[1]); f0.z = b2f(tmp[2]); f0.w = b2f(tmp[3]);
        f1.x = b2f(tmp[4]); f1.y = b2f(tmp[5]); f1.z = b2f(tmp[6]); f1.w = b2f(tmp[7]);
        *(float4*)&w0[base] = f0;
        *(float4*)&w0[base + 4] = f1;
    }
}

// ---------------------------------------------------------------------------
// Upsample scale into concat cols [col0, col0+256). bf16 in/out.
// ---------------------------------------------------------------------------
__global__ __launch_bounds__(256) void upsample_kernel(
    const ushort* __restrict__ y, ushort* __restrict__ ccat, int L, int s, int col0)
{
    int idx = blockIdx.x * 256 + threadIdx.x;
    int c4 = (idx & 63) * 4;
    int t = (idx >> 6) & 2047;
    int b = idx >> 17;
    int k = t / s, j = t - k * s;
    float a = (float)j / (float)s;
    const ushort* y0p = y + ((long)(b * L + k)) * 256 + c4;
    ushort4 y0 = *(const ushort4*)y0p;
    ushort4 y1 = {0, 0, 0, 0};
    if (k + 1 < L) y1 = *(const ushort4*)(y0p + 256);
    ushort4 o;
    o.x = f2b((1.f - a) * b2f(y0.x) + a * b2f(y1.x));
    o.y = f2b((1.f - a) * b2f(y0.y) + a * b2f(y1.y));
    o.z = f2b((1.f - a) * b2f(y0.z) + a * b2f(y1.z));
    o.w = f2b((1.f - a) * b2f(y0.w) + a * b2f(y1.w));
    *(ushort4*)&ccat[((long)(b * 2048 + t)) * 1024 + col0 + c4] = o;
}

// ---------------------------------------------------------------------------
// LayerNorm in place on fp32 rows of 1024.
// ---------------------------------------------------------------------------
__global__ __launch_bounds__(256) void ln_kernel(
    float* __restrict__ zbuf, const float* __restrict__ g, const float* __restrict__ bta)
{
    long row = blockIdx.x;
    float* p = zbuf + row * 1024;
    const int tid = threadIdx.x;
    float v[4];
    float s = 0.f;
    #pragma unroll
    for (int j = 0; j < 4; ++j) { v[j] = p[tid + (j << 8)]; s += v[j]; }
    #pragma unroll
    for (int off = 32; off; off >>= 1) s += __shfl_xor(s, off);
    __shared__ float r0[4], r1[4];
    int wid = tid >> 6;
    if ((tid & 63) == 0) r0[wid] = s;
    __syncthreads();
    s = r0[0] + r0[1] + r0[2] + r0[3];
    float mu = s * (1.f / 1024.f);
    float q = 0.f;
    #pragma unroll
    for (int j = 0; j < 4; ++j) { float d = v[j] - mu; q += d * d; }
    #pragma unroll
    for (int off = 32; off; off >>= 1) q += __shfl_xor(q, off);
    if ((tid & 63) == 0) r1[wid] = q;
    __syncthreads();
    q = r1[0] + r1[1] + r1[2] + r1[3];
    float rstd = rsqrtf(q * (1.f / 1024.f) + 1e-5f);
    #pragma unroll
    for (int j = 0; j < 4; ++j) {
        int c = tid + (j << 8);
        p[c] = (v[j] - mu) * rstd * g[c] + bta[c];
    }
}

// ---------------------------------------------------------------------------
extern "C" void kernel_launch(void* const* d_in, const int* in_sizes, int n_in,
                              void* d_out, int out_size, void* d_ws, size_t ws_size,
                              hipStream_t stream)
{
    const float* x     = (const float*)d_in[0];
    const float* projW = (const float*)d_in[1];
    const float* projB = (const float*)d_in[2];
    const float* inW   = (const float*)d_in[3];
    const float* inB   = (const float*)d_in[4];
    const float* outW  = (const float*)d_in[5];
    const float* outB  = (const float*)d_in[6];
    const float* fusW  = (const float*)d_in[7];
    const float* fusB  = (const float*)d_in[8];
    const float* lnG   = (const float*)d_in[9];
    const float* lnB   = (const float*)d_in[10];

    float* fused  = (float*)d_out;
    float* out_w0 = fused + 8388608;

    // workspace layout (bytes; ~85 MB)
    char* w = (char*)d_ws;
    ushort* xb     = (ushort*)w; w += 16777216;   // x bf16 [8192][1024]
    ushort* pT     = (ushort*)w; w += 2097152;    // projW^T [4][256][1024]
    ushort* iT     = (ushort*)w; w += 1572864;    // inW^T   [4][768][256]
    ushort* oT     = (ushort*)w; w += 524288;     // outW^T  [4][256][256]
    ushort* fT     = (ushort*)w; w += 2097152;    // fusW^T  [1024][1024]
    ushort* xprojb = (ushort*)w; w += 7864320;    // [15360][256]
    ushort* qkvb   = (ushort*)w; w += 23592960;   // [15360][768]
    ushort* ob     = (ushort*)w; w += 7864320;    // attn out [15360][256]
    ushort* yallb  = (ushort*)w; w += 7864320;    // out-proj [15360][256]
    ushort* ccatb  = (ushort*)w; w += 16777216;   // concat [8192][1024]
    ushort* vTb    = (ushort*)w; w += 4194304;    // V^T [16][64][Lmax]
    float*  msc    = (float*)w;  w += 131072;     // [16*2048]
    float*  invl   = (float*)w;  w += 131072;     // [16*2048]

    const int Ls_[4] = {2048, 1024, 512, 256};
    const int ss_[4] = {1, 2, 4, 8};
    const int Rr_[4] = {0, 8192, 12288, 14336};
    const int BIG = 1 << 30;

    // 0) converts + weight transposes
    cvt_kernel<<<8192, 256, 0, stream>>>(x, xb, 8388608);
    wtrans_kernel<<<dim3(8, 32, 4), 256, 0, stream>>>(projW, pT, 1024, 256);
    wtrans_kernel<<<dim3(24, 8, 4), 256, 0, stream>>>(inW, iT, 256, 768);
    wtrans_kernel<<<dim3(8, 8, 4), 256, 0, stream>>>(outW, oT, 256, 256);
    wtrans_kernel<<<dim3(32, 32, 1), 256, 0, stream>>>(fusW, fT, 1024, 1024);

    // 1) proj (subsample-first gather)
    for (int i = 0; i < 4; ++i) {
        int L = Ls_[i], M = 4 * L;
        gemm_mfma<true><<<dim3(M / 128, 2, 1), 256, 0, stream>>>(
            xb, 0, 0, L, (long)2097152, ss_[i] * 1024,
            pT + (long)i * 262144, 0, 0, 1024,
            projB + i * 256,
            xprojb + (long)Rr_[i] * 256, 0, 0, 256, 0, 1.f, M, 256, 1024);
    }
    // 2) QKV
    for (int i = 0; i < 4; ++i) {
        int L = Ls_[i], M = 4 * L;
        gemm_mfma<true><<<dim3(M / 128, 6, 1), 256, 0, stream>>>(
            xprojb + (long)Rr_[i] * 256, 0, 0, BIG, 0, 256,
            iT + (long)i * 196608, 0, 0, 256,
            inB + i * 768,
            qkvb + (long)Rr_[i] * 768, 0, 0, 768, 0, 1.f, M, 768, 256);
    }
    // 3) per-scale fused flash attention -> out-proj -> upsample
    for (int i = 0; i < 4; ++i) {
        int L = Ls_[i], M = 4 * L;
        const ushort* qkv_i = qkvb + (long)Rr_[i] * 768;
        vtrans_kernel<<<dim3(L / 64, 1, 16), 256, 0, stream>>>(qkv_i, vTb, L);
        if (i == 0) {
            attn_flash<true><<<dim3(L / 128, 1, 16), 256, 0, stream>>>(
                qkv_i, vTb, ob + (long)Rr_[i] * 256, msc, invl, L);
            w0_recompute<<<dim3(16, 16, 4), 256, 0, stream>>>(qkv_i, msc, invl, out_w0);
        } else {
            attn_flash<false><<<dim3(L / 128, 1, 16), 256, 0, stream>>>(
                qkv_i, vTb, ob + (long)Rr_[i] * 256, msc, invl, L);
        }
        gemm_mfma<true><<<dim3(M / 128, 2, 1), 256, 0, stream>>>(
            ob + (long)Rr_[i] * 256, 0, 0, BIG, 0, 256,
            oT + (long)i * 65536, 0, 0, 256,
            outB + i * 256,
            yallb + (long)Rr_[i] * 256, 0, 0, 256, 0, 1.f, M, 256, 256);
        upsample_kernel<<<2048, 256, 0, stream>>>(
            yallb + (long)Rr_[i] * 256, ccatb, L, ss_[i], i * 256);
    }
    // 4) fusion GEMM -> fp32 d_out, then LN
    gemm_mfma<true><<<dim3(64, 8, 1), 256, 0, stream>>>(
        ccatb, 0, 0, BIG, 0, 1024,
        fT, 0, 0, 1024,
        fusB,
        fused, 0, 0, 1024, 1, 1.f, 8192, 1024, 1024);
    ln_kernel<<<8192, 256, 0, stream>>>(fused, lnG, lnB);
}

// Round 4
// 348.502 us; speedup vs baseline: 5.1953x; 1.5282x over previous
//
#include <hip/hip_runtime.h>
#include <hip/hip_bf16.h>

// B=4, S=2048, D_MODEL=1024, NS=4 scales (1,2,4,8), E=256, H=4, DK=64
// out = [fused (4*2048*1024) fp32] ++ [w0 (4*2048*2048) fp32]
// Scale row bases Rr = {0, 8192, 12288, 14336} = 16384 - (16384>>s)

typedef short bh8 __attribute__((ext_vector_type(8)));   // 8 bf16 (4 VGPRs)
typedef float f32x4 __attribute__((ext_vector_type(4)));

__device__ __forceinline__ ushort f2b(float f) {
    __hip_bfloat16 h = __float2bfloat16(f);
    return *reinterpret_cast<ushort*>(&h);
}
__device__ __forceinline__ float b2f(ushort u) {
    __hip_bfloat16 h;
    *reinterpret_cast<ushort*>(&h) = u;
    return __bfloat162float(h);
}

// ---------------------------------------------------------------------------
// fp32 -> bf16 bulk convert
// ---------------------------------------------------------------------------
__global__ __launch_bounds__(256) void cvt_kernel(
    const float* __restrict__ s, ushort* __restrict__ d, long n)
{
    long i = ((long)blockIdx.x * 256 + threadIdx.x) * 4;
    if (i >= n) return;
    float4 v = *(const float4*)(s + i);
    ushort4 o;
    o.x = f2b(v.x); o.y = f2b(v.y); o.z = f2b(v.z); o.w = f2b(v.w);
    *(ushort4*)(d + i) = o;
}

// ---------------------------------------------------------------------------
// Weight transpose+convert: src fp32 [K][N] (batch z) -> dst bf16 [N][K]
// ---------------------------------------------------------------------------
__global__ __launch_bounds__(256) void wtrans_kernel(
    const float* __restrict__ src, ushort* __restrict__ dst, int K, int N)
{
    __shared__ float Ls[32][33];
    const int n0 = blockIdx.x * 32, k0 = blockIdx.y * 32;
    const float* s = src + (long)blockIdx.z * K * N;
    ushort* d = dst + (long)blockIdx.z * N * K;
    const int tid = threadIdx.x;
    #pragma unroll
    for (int it = 0; it < 4; ++it) {
        int f = tid + it * 256;
        int kc = f >> 5, rn = f & 31;
        Ls[kc][rn] = s[(long)(k0 + kc) * N + n0 + rn];
    }
    __syncthreads();
    #pragma unroll
    for (int it = 0; it < 2; ++it) {
        int f = tid + it * 256;
        int rn = f >> 4, kc2 = (f & 15) * 2;
        ushort2 o;
        o.x = f2b(Ls[kc2][rn]);
        o.y = f2b(Ls[kc2 + 1][rn]);
        *(ushort2*)&d[(long)(n0 + rn) * K + k0 + kc2] = o;
    }
}

// ---------------------------------------------------------------------------
// Merged multi-scale GEMM, M=15360 rows with per-m-tile scale lookup.
// MODE 0: proj  (A = xb gather-subsampled, K=1024, N=256, C=xprojb)
// MODE 1: qkv   (A = xprojb,               K=256,  N=768, C=qkvb)
// MODE 2: oproj (A = ob,                   K=256,  N=256, C=yallb)
// Weight Wt: per-scale pre-transposed bf16 [N][K]; bias fp32 per scale [N].
// ---------------------------------------------------------------------------
template<int MODE>
__global__ __launch_bounds__(256) void gemm_ms(
    const ushort* __restrict__ A, const ushort* __restrict__ Wt,
    const float* __restrict__ bias, ushort* __restrict__ C)
{
    constexpr int K = (MODE == 0) ? 1024 : 256;
    constexpr int N = (MODE == 1) ? 768 : 256;
    __shared__ ushort As[128][72];
    __shared__ ushort Bs[128][72];

    const int tid = threadIdx.x;
    const int wave = tid >> 6, lane = tid & 63;
    const int lm = lane & 15, quad = lane >> 4;
    const int wm = (wave & 1) * 64, wn = (wave >> 1) * 64;
    const int m0 = blockIdx.x * 128, n0 = blockIdx.y * 128;
    const int s = (m0 >= 14336) ? 3 : ((m0 >= 12288) ? 2 : ((m0 >= 8192) ? 1 : 0));
    const ushort* Wp = Wt + (long)s * N * K;
    const float* bp_ = bias + s * N;

    f32x4 acc[4][4];
    #pragma unroll
    for (int i = 0; i < 4; ++i)
        #pragma unroll
        for (int j = 0; j < 4; ++j) {
            f32x4 zz = {0.f, 0.f, 0.f, 0.f};
            acc[i][j] = zz;
        }

    const int r0 = tid >> 3, k8 = (tid & 7) * 8;
    const ushort* ap[4];
    #pragma unroll
    for (int it = 0; it < 4; ++it) {
        int m = m0 + r0 + it * 32;
        if (MODE == 0) {
            int t = m - (16384 - (16384 >> s));
            int b = t >> (11 - s);
            int tt = t - (b << (11 - s));
            ap[it] = A + ((long)(b * 2048) + ((long)tt << s)) * 1024 + k8;
        } else {
            ap[it] = A + (long)m * K + k8;
        }
    }
    const ushort* bp[4];
    #pragma unroll
    for (int it = 0; it < 4; ++it)
        bp[it] = Wp + (long)(n0 + r0 + it * 32) * K + k8;

    for (int k0 = 0; k0 < K; k0 += 64) {
        #pragma unroll
        for (int it = 0; it < 4; ++it)
            *(bh8*)&As[r0 + it * 32][k8] = *(const bh8*)(ap[it] + k0);
        #pragma unroll
        for (int it = 0; it < 4; ++it)
            *(bh8*)&Bs[r0 + it * 32][k8] = *(const bh8*)(bp[it] + k0);
        __syncthreads();
        #pragma unroll
        for (int ks = 0; ks < 2; ++ks) {
            bh8 af[4], bfv[4];
            #pragma unroll
            for (int i = 0; i < 4; ++i)
                af[i] = *(const bh8*)&As[wm + i * 16 + lm][ks * 32 + quad * 8];
            #pragma unroll
            for (int j = 0; j < 4; ++j)
                bfv[j] = *(const bh8*)&Bs[wn + j * 16 + lm][ks * 32 + quad * 8];
            #pragma unroll
            for (int i = 0; i < 4; ++i)
                #pragma unroll
                for (int j = 0; j < 4; ++j)
                    acc[i][j] = __builtin_amdgcn_mfma_f32_16x16x32_bf16(
                        af[i], bfv[j], acc[i][j], 0, 0, 0);
        }
        __syncthreads();
    }

    float bv[4]; int cols[4];
    #pragma unroll
    for (int j = 0; j < 4; ++j) {
        cols[j] = n0 + wn + j * 16 + lm;
        bv[j] = bp_[cols[j]];
    }
    #pragma unroll
    for (int i = 0; i < 4; ++i) {
        int mb = m0 + wm + i * 16 + quad * 4;
        #pragma unroll
        for (int j = 0; j < 4; ++j)
            #pragma unroll
            for (int r = 0; r < 4; ++r)
                C[(long)(mb + r) * N + cols[j]] = f2b(acc[i][j][r] + bv[j]);
    }
}

// ---------------------------------------------------------------------------
// Merged V transpose, all scales. grid 960 blocks (512/256/128/64 per scale).
// qkv rows [(Rr+b*L+k)][768] col 512+h*64+d -> vT[scale][z][d][k]
// ---------------------------------------------------------------------------
__global__ __launch_bounds__(256) void vtrans_ms(
    const ushort* __restrict__ qkvb, ushort* __restrict__ vTb)
{
    __shared__ ushort Ls[64][72];
    const int bid = blockIdx.x;
    const int s = (bid >= 896) ? 3 : ((bid >= 768) ? 2 : ((bid >= 512) ? 1 : 0));
    const int rel = bid - ((s == 0) ? 0 : ((s == 1) ? 512 : ((s == 2) ? 768 : 896)));
    const int L = 2048 >> s;
    const int z = rel >> (5 - s);
    const int kt = rel & ((32 >> s) - 1);
    const int b = z >> 2, h = z & 3;
    const ushort* src = qkvb + (long)(16384 - (16384 >> s)) * 768
                        + (long)b * L * 768 + 512 + h * 64;
    const int k0 = kt * 64;
    const int tid = threadIdx.x;
    const int kk = tid >> 3, d8 = (tid & 7) * 8;
    #pragma unroll
    for (int it = 0; it < 2; ++it) {
        int k = kk + it * 32;
        bh8 v = *(const bh8*)(src + (long)(k0 + k) * 768 + d8);
        ushort tmp[8];
        *(bh8*)tmp = v;
        #pragma unroll
        for (int j = 0; j < 8; ++j) Ls[d8 + j][k] = tmp[j];
    }
    __syncthreads();
    ushort* dst = vTb + (long)(4096 - (4096 >> s)) * 1024 + (long)z * 64 * L;
    #pragma unroll
    for (int it = 0; it < 2; ++it) {
        int d = kk + it * 32;
        *(bh8*)(dst + (long)d * L + k0 + d8) = *(const bh8*)&Ls[d][d8];
    }
}

// ---------------------------------------------------------------------------
// Merged flash attention, all scales in one dispatch. BQ=64, BK=128, D=64.
// grid 960 blocks; 4 waves/block, each wave owns 16 q-rows.
// Scale 0 also stores per-row (0.125*m, 1/l) for w0 recompute.
// LDS 52 KB -> 3 blocks/CU.
// ---------------------------------------------------------------------------
__global__ __launch_bounds__(256, 3) void attn_ms(
    const ushort* __restrict__ qkvb, const ushort* __restrict__ vTb,
    ushort* __restrict__ ob, float* __restrict__ msc, float* __restrict__ invl)
{
    __shared__ ushort Ks[128 * 72];   // [k][d] stride 72
    __shared__ ushort Vs[64 * 136];   // [d][k] stride 136
    __shared__ ushort Ps[64 * 136];   // [q][k] stride 136 (also Q staging)

    const int bid = blockIdx.x;
    const int s = (bid >= 896) ? 3 : ((bid >= 768) ? 2 : ((bid >= 512) ? 1 : 0));
    const int rel = bid - ((s == 0) ? 0 : ((s == 1) ? 512 : ((s == 2) ? 768 : 896)));
    const int L = 2048 >> s;
    const int z = rel >> (5 - s);
    const int qt = rel & ((32 >> s) - 1);
    const int b = z >> 2, h = z & 3;
    const int Rr16 = 16384 - (16384 >> s);
    const ushort* qbase = qkvb + (long)Rr16 * 768 + (long)b * L * 768 + h * 64;
    const ushort* kbase = qbase + 256;
    const ushort* vbase = vTb + (long)(4096 - (4096 >> s)) * 1024 + (long)z * 64 * L;
    ushort* o = ob + (long)Rr16 * 256;

    const int tid = threadIdx.x;
    const int wave = tid >> 6, lane = tid & 63;
    const int lm = lane & 15, quad = lane >> 4;
    const int wm = wave * 16;
    const int q0 = qt * 64;
    const int r0 = tid >> 3, k8 = (tid & 7) * 8;
    const int vd0 = tid >> 4, vc8 = (tid & 15) * 8;

    // stage Q tile (64x64) into Ps, pull A-frags to regs (rows are wave-private)
    #pragma unroll
    for (int it = 0; it < 2; ++it) {
        int row = r0 + it * 32;
        *(bh8*)&Ps[row * 136 + k8] = *(const bh8*)(qbase + (long)(q0 + row) * 768 + k8);
    }
    __syncthreads();
    bh8 qf[2];
    #pragma unroll
    for (int ks = 0; ks < 2; ++ks)
        qf[ks] = *(const bh8*)&Ps[(wm + lm) * 136 + ks * 32 + quad * 8];

    f32x4 oc[4];
    #pragma unroll
    for (int nj = 0; nj < 4; ++nj) {
        f32x4 zz = {0.f, 0.f, 0.f, 0.f};
        oc[nj] = zz;
    }
    float m_run[4], l_run[4];
    #pragma unroll
    for (int rr = 0; rr < 4; ++rr) { m_run[rr] = -3.0e38f; l_run[rr] = 0.f; }

    for (int k0 = 0; k0 < L; k0 += 128) {
        #pragma unroll
        for (int it = 0; it < 4; ++it) {
            int row = r0 + it * 32;
            *(bh8*)&Ks[row * 72 + k8] = *(const bh8*)(kbase + (long)(k0 + row) * 768 + k8);
        }
        #pragma unroll
        for (int it = 0; it < 4; ++it) {
            int d = vd0 + it * 16;
            *(bh8*)&Vs[d * 136 + vc8] = *(const bh8*)(vbase + (long)d * L + k0 + vc8);
        }
        __syncthreads();

        f32x4 sc[8];
        #pragma unroll
        for (int nj = 0; nj < 8; ++nj) {
            f32x4 zz = {0.f, 0.f, 0.f, 0.f};
            sc[nj] = zz;
        }
        #pragma unroll
        for (int ks = 0; ks < 2; ++ks)
            #pragma unroll
            for (int nj = 0; nj < 8; ++nj) {
                bh8 kf = *(const bh8*)&Ks[(nj * 16 + lm) * 72 + ks * 32 + quad * 8];
                sc[nj] = __builtin_amdgcn_mfma_f32_16x16x32_bf16(qf[ks], kf, sc[nj], 0, 0, 0);
            }

        // online softmax; P -> Ps rows (wave-private)
        #pragma unroll
        for (int rr = 0; rr < 4; ++rr) {
            float t = sc[0][rr];
            #pragma unroll
            for (int nj = 1; nj < 8; ++nj) t = fmaxf(t, sc[nj][rr]);
            t = fmaxf(t, __shfl_xor(t, 1));
            t = fmaxf(t, __shfl_xor(t, 2));
            t = fmaxf(t, __shfl_xor(t, 4));
            t = fmaxf(t, __shfl_xor(t, 8));
            float mo = m_run[rr];
            float mn = fmaxf(mo, t);
            float alpha = __expf(0.125f * (mo - mn));
            m_run[rr] = mn;
            float rs = 0.f;
            int prow = (wm + quad * 4 + rr) * 136;
            #pragma unroll
            for (int nj = 0; nj < 8; ++nj) {
                float p = __expf(0.125f * (sc[nj][rr] - mn));
                rs += p;
                Ps[prow + nj * 16 + lm] = f2b(p);
            }
            rs += __shfl_xor(rs, 1);
            rs += __shfl_xor(rs, 2);
            rs += __shfl_xor(rs, 4);
            rs += __shfl_xor(rs, 8);
            l_run[rr] = l_run[rr] * alpha + rs;
            #pragma unroll
            for (int nj = 0; nj < 4; ++nj) oc[nj][rr] *= alpha;
        }

        // O += P V
        #pragma unroll
        for (int kst = 0; kst < 4; ++kst) {
            bh8 pf = *(const bh8*)&Ps[(wm + lm) * 136 + kst * 32 + quad * 8];
            #pragma unroll
            for (int nj = 0; nj < 4; ++nj) {
                bh8 vf = *(const bh8*)&Vs[(nj * 16 + lm) * 136 + kst * 32 + quad * 8];
                oc[nj] = __builtin_amdgcn_mfma_f32_16x16x32_bf16(pf, vf, oc[nj], 0, 0, 0);
            }
        }
        __syncthreads();
    }

    #pragma unroll
    for (int rr = 0; rr < 4; ++rr) {
        float il = 1.f / l_run[rr];
        int q = q0 + wm + quad * 4 + rr;
        if (s == 0 && lm == 0) {
            msc[z * 2048 + q] = 0.125f * m_run[rr];
            invl[z * 2048 + q] = il;
        }
        long rbase = ((long)(b * L + q)) * 256 + h * 64;
        #pragma unroll
        for (int nj = 0; nj < 4; ++nj)
            o[rbase + nj * 16 + lm] = f2b(oc[nj][rr] * il);
    }
}

// ---------------------------------------------------------------------------
// w0 = mean over heads of probs, recomputed from Q,K + saved (0.125*m, 1/l).
// grid (16 q-tiles, 16 k-tiles, 4 b). Coalesced fp32 output via LDS staging.
// ---------------------------------------------------------------------------
__global__ __launch_bounds__(256, 2) void w0_recompute(
    const ushort* __restrict__ qkv,
    const float* __restrict__ msc, const float* __restrict__ invl,
    float* __restrict__ w0)
{
    const int L = 2048;
    __shared__ ushort Qs[128 * 72];
    __shared__ ushort Ks[128 * 72];
    __shared__ ushort Ws[128 * 136];

    const int tid = threadIdx.x;
    const int wave = tid >> 6, lane = tid & 63;
    const int lm = lane & 15, quad = lane >> 4;
    const int wm = wave * 32;
    const int q0 = blockIdx.x * 128, k0 = blockIdx.y * 128;
    const int b = blockIdx.z;
    const int r0 = tid >> 3, k8 = (tid & 7) * 8;

    f32x4 acc[2][8];
    #pragma unroll
    for (int mi = 0; mi < 2; ++mi)
        #pragma unroll
        for (int nj = 0; nj < 8; ++nj) {
            f32x4 zz = {0.f, 0.f, 0.f, 0.f};
            acc[mi][nj] = zz;
        }

    for (int h = 0; h < 4; ++h) {
        const ushort* qb = qkv + (long)b * L * 768 + h * 64;
        const ushort* kb = qb + 256;
        #pragma unroll
        for (int it = 0; it < 4; ++it) {
            int r = r0 + it * 32;
            *(bh8*)&Qs[r * 72 + k8] = *(const bh8*)(qb + (long)(q0 + r) * 768 + k8);
            *(bh8*)&Ks[r * 72 + k8] = *(const bh8*)(kb + (long)(k0 + r) * 768 + k8);
        }
        __syncthreads();
        bh8 qf[2][2];
        #pragma unroll
        for (int mi = 0; mi < 2; ++mi)
            #pragma unroll
            for (int ks = 0; ks < 2; ++ks)
                qf[mi][ks] = *(const bh8*)&Qs[(wm + mi * 16 + lm) * 72 + ks * 32 + quad * 8];
        f32x4 sc[2][8];
        #pragma unroll
        for (int mi = 0; mi < 2; ++mi)
            #pragma unroll
            for (int nj = 0; nj < 8; ++nj) {
                f32x4 zz = {0.f, 0.f, 0.f, 0.f};
                sc[mi][nj] = zz;
            }
        #pragma unroll
        for (int ks = 0; ks < 2; ++ks)
            #pragma unroll
            for (int nj = 0; nj < 8; ++nj) {
                bh8 kf = *(const bh8*)&Ks[(nj * 16 + lm) * 72 + ks * 32 + quad * 8];
                #pragma unroll
                for (int mi = 0; mi < 2; ++mi)
                    sc[mi][nj] = __builtin_amdgcn_mfma_f32_16x16x32_bf16(
                        qf[mi][ks], kf, sc[mi][nj], 0, 0, 0);
            }
        const float* mz = msc + (long)(b * 4 + h) * L;
        const float* iz = invl + (long)(b * 4 + h) * L;
        #pragma unroll
        for (int mi = 0; mi < 2; ++mi)
            #pragma unroll
            for (int rr = 0; rr < 4; ++rr) {
                int q = q0 + wm + mi * 16 + quad * 4 + rr;
                float mv = mz[q], iv = iz[q];
                #pragma unroll
                for (int nj = 0; nj < 8; ++nj)
                    acc[mi][nj][rr] += __expf(0.125f * sc[mi][nj][rr] - mv) * iv;
            }
        __syncthreads();
    }

    #pragma unroll
    for (int mi = 0; mi < 2; ++mi)
        #pragma unroll
        for (int rr = 0; rr < 4; ++rr) {
            int prow = (wm + mi * 16 + quad * 4 + rr) * 136;
            #pragma unroll
            for (int nj = 0; nj < 8; ++nj)
                Ws[prow + nj * 16 + lm] = f2b(0.25f * acc[mi][nj][rr]);
        }
    __syncthreads();
    #pragma unroll
    for (int it = 0; it < 8; ++it) {
        int idx = tid + it * 256;
        int row = idx >> 4, c8 = (idx & 15) * 8;
        ushort tmp[8];
        *(bh8*)tmp = *(const bh8*)&Ws[row * 136 + c8];
        long base = ((long)b * 2048 + q0 + row) * 2048 + k0 + c8;
        float4 f0, f1;
        f0.x = b2f(tmp[0]); f0.y = b2f(tmp[1]); f0.z = b2f(tmp[2]); f0.w = b2f(tmp[3]);
        f1.x = b2f(tmp[4]); f1.y = b2f(tmp[5]); f1.z = b2f(tmp[6]); f1.w = b2f(tmp[7]);
        *(float4*)&w0[base] = f0;
        *(float4*)&w0[base + 4] = f1;
    }
}

// ---------------------------------------------------------------------------
// Merged upsample, all scales. grid 8192 blocks (2048 per scale).
// ---------------------------------------------------------------------------
__global__ __launch_bounds__(256) void upsample_ms(
    const ushort* __restrict__ yallb, ushort* __restrict__ ccat)
{
    const int bid = blockIdx.x;
    const int s = bid >> 11;
    const int idx = (bid & 2047) * 256 + threadIdx.x;
    const int c4 = (idx & 63) * 4;
    const int t = (idx >> 6) & 2047;
    const int b = idx >> 17;
    const int L = 2048 >> s;
    const int k = t >> s, j = t & ((1 << s) - 1);
    const float a = (float)j / (float)(1 << s);
    const ushort* y = yallb + (long)(16384 - (16384 >> s)) * 256;
    const ushort* y0p = y + ((long)(b * L + k)) * 256 + c4;
    ushort4 y0 = *(const ushort4*)y0p;
    ushort4 y1 = {0, 0, 0, 0};
    if (k + 1 < L) y1 = *(const ushort4*)(y0p + 256);
    ushort4 o;
    o.x = f2b((1.f - a) * b2f(y0.x) + a * b2f(y1.x));
    o.y = f2b((1.f - a) * b2f(y0.y) + a * b2f(y1.y));
    o.z = f2b((1.f - a) * b2f(y0.z) + a * b2f(y1.z));
    o.w = f2b((1.f - a) * b2f(y0.w) + a * b2f(y1.w));
    *(ushort4*)&ccat[((long)(b * 2048 + t)) * 1024 + s * 256 + c4] = o;
}

// ---------------------------------------------------------------------------
// Fusion GEMM: fused[8192][1024] = ccat[8192][1024] @ fusW + fusB (fp32 out)
// 128x128 tile.
// ---------------------------------------------------------------------------
__global__ __launch_bounds__(256) void gemm_fus(
    const ushort* __restrict__ A, const ushort* __restrict__ Wt,
    const float* __restrict__ bias, float* __restrict__ C)
{
    const int K = 1024, N = 1024;
    __shared__ ushort As[128][72];
    __shared__ ushort Bs[128][72];
    const int tid = threadIdx.x;
    const int wave = tid >> 6, lane = tid & 63;
    const int lm = lane & 15, quad = lane >> 4;
    const int wm = (wave & 1) * 64, wn = (wave >> 1) * 64;
    const int m0 = blockIdx.x * 128, n0 = blockIdx.y * 128;

    f32x4 acc[4][4];
    #pragma unroll
    for (int i = 0; i < 4; ++i)
        #pragma unroll
        for (int j = 0; j < 4; ++j) {
            f32x4 zz = {0.f, 0.f, 0.f, 0.f};
            acc[i][j] = zz;
        }
    const int r0 = tid >> 3, k8 = (tid & 7) * 8;
    for (int k0 = 0; k0 < K; k0 += 64) {
        #pragma unroll
        for (int it = 0; it < 4; ++it) {
            int r = r0 + it * 32;
            *(bh8*)&As[r][k8] = *(const bh8*)(A + (long)(m0 + r) * K + k0 + k8);
            *(bh8*)&Bs[r][k8] = *(const bh8*)(Wt + (long)(n0 + r) * K + k0 + k8);
        }
        __syncthreads();
        #pragma unroll
        for (int ks = 0; ks < 2; ++ks) {
            bh8 af[4], bfv[4];
            #pragma unroll
            for (int i = 0; i < 4; ++i)
                af[i] = *(const bh8*)&As[wm + i * 16 + lm][ks * 32 + quad * 8];
            #pragma unroll
            for (int j = 0; j < 4; ++j)
                bfv[j] = *(const bh8*)&Bs[wn + j * 16 + lm][ks * 32 + quad * 8];
            #pragma unroll
            for (int i = 0; i < 4; ++i)
                #pragma unroll
                for (int j = 0; j < 4; ++j)
                    acc[i][j] = __builtin_amdgcn_mfma_f32_16x16x32_bf16(
                        af[i], bfv[j], acc[i][j], 0, 0, 0);
        }
        __syncthreads();
    }
    float bv[4]; int cols[4];
    #pragma unroll
    for (int j = 0; j < 4; ++j) {
        cols[j] = n0 + wn + j * 16 + lm;
        bv[j] = bias[cols[j]];
    }
    #pragma unroll
    for (int i = 0; i < 4; ++i) {
        int mb = m0 + wm + i * 16 + quad * 4;
        #pragma unroll
        for (int j = 0; j < 4; ++j)
            #pragma unroll
            for (int r = 0; r < 4; ++r)
                C[(long)(mb + r) * N + cols[j]] = acc[i][j][r] + bv[j];
    }
}

// ---------------------------------------------------------------------------
// LayerNorm in place on fp32 rows of 1024.
// ---------------------------------------------------------------------------
__global__ __launch_bounds__(256) void ln_kernel(
    float* __restrict__ zbuf, const float* __restrict__ g, const float* __restrict__ bta)
{
    long row = blockIdx.x;
    float* p = zbuf + row * 1024;
    const int tid = threadIdx.x;
    float v[4];
    float s = 0.f;
    #pragma unroll
    for (int j = 0; j < 4; ++j) { v[j] = p[tid + (j << 8)]; s += v[j]; }
    #pragma unroll
    for (int off = 32; off; off >>= 1) s += __shfl_xor(s, off);
    __shared__ float r0[4], r1[4];
    int wid = tid >> 6;
    if ((tid & 63) == 0) r0[wid] = s;
    __syncthreads();
    s = r0[0] + r0[1] + r0[2] + r0[3];
    float mu = s * (1.f / 1024.f);
    float q = 0.f;
    #pragma unroll
    for (int j = 0; j < 4; ++j) { float d = v[j] - mu; q += d * d; }
    #pragma unroll
    for (int off = 32; off; off >>= 1) q += __shfl_xor(q, off);
    if ((tid & 63) == 0) r1[wid] = q;
    __syncthreads();
    q = r1[0] + r1[1] + r1[2] + r1[3];
    float rstd = rsqrtf(q * (1.f / 1024.f) + 1e-5f);
    #pragma unroll
    for (int j = 0; j < 4; ++j) {
        int c = tid + (j << 8);
        p[c] = (v[j] - mu) * rstd * g[c] + bta[c];
    }
}

// ---------------------------------------------------------------------------
extern "C" void kernel_launch(void* const* d_in, const int* in_sizes, int n_in,
                              void* d_out, int out_size, void* d_ws, size_t ws_size,
                              hipStream_t stream)
{
    const float* x     = (const float*)d_in[0];
    const float* projW = (const float*)d_in[1];
    const float* projB = (const float*)d_in[2];
    const float* inW   = (const float*)d_in[3];
    const float* inB   = (const float*)d_in[4];
    const float* outW  = (const float*)d_in[5];
    const float* outB  = (const float*)d_in[6];
    const float* fusW  = (const float*)d_in[7];
    const float* fusB  = (const float*)d_in[8];
    const float* lnG   = (const float*)d_in[9];
    const float* lnB   = (const float*)d_in[10];

    float* fused  = (float*)d_out;
    float* out_w0 = fused + 8388608;

    // workspace layout (bytes; ~95 MB)
    char* w = (char*)d_ws;
    ushort* xb     = (ushort*)w; w += 16777216;   // x bf16 [8192][1024]
    ushort* pT     = (ushort*)w; w += 2097152;    // projW^T [4][256][1024]
    ushort* iT     = (ushort*)w; w += 1572864;    // inW^T   [4][768][256]
    ushort* oT     = (ushort*)w; w += 524288;     // outW^T  [4][256][256]
    ushort* fT     = (ushort*)w; w += 2097152;    // fusW^T  [1024][1024]
    ushort* xprojb = (ushort*)w; w += 7864320;    // [15360][256]
    ushort* qkvb   = (ushort*)w; w += 23592960;   // [15360][768]
    ushort* ob     = (ushort*)w; w += 7864320;    // attn out [15360][256]
    ushort* yallb  = (ushort*)w; w += 7864320;    // out-proj [15360][256]
    ushort* ccatb  = (ushort*)w; w += 16777216;   // concat [8192][1024]
    ushort* vTb    = (ushort*)w; w += 7864320;    // V^T all scales [3840*1024]
    float*  msc    = (float*)w;  w += 131072;     // [16*2048]
    float*  invl   = (float*)w;  w += 131072;     // [16*2048]

    // 0) converts + weight transposes
    cvt_kernel<<<8192, 256, 0, stream>>>(x, xb, 8388608);
    wtrans_kernel<<<dim3(8, 32, 4), 256, 0, stream>>>(projW, pT, 1024, 256);
    wtrans_kernel<<<dim3(24, 8, 4), 256, 0, stream>>>(inW, iT, 256, 768);
    wtrans_kernel<<<dim3(8, 8, 4), 256, 0, stream>>>(outW, oT, 256, 256);
    wtrans_kernel<<<dim3(32, 32, 1), 256, 0, stream>>>(fusW, fT, 1024, 1024);

    // 1) proj (all scales, gather-subsample) -> xprojb
    gemm_ms<0><<<dim3(120, 2), 256, 0, stream>>>(xb, pT, projB, xprojb);
    // 2) QKV (all scales) -> qkvb
    gemm_ms<1><<<dim3(120, 6), 256, 0, stream>>>(xprojb, iT, inB, qkvb);
    // 3) V transpose (all scales)
    vtrans_ms<<<960, 256, 0, stream>>>(qkvb, vTb);
    // 4) flash attention (all scales) -> ob; scale0 saves (m, 1/l)
    attn_ms<<<960, 256, 0, stream>>>(qkvb, vTb, ob, msc, invl);
    // 5) w0 recompute from scale-0 Q,K
    w0_recompute<<<dim3(16, 16, 4), 256, 0, stream>>>(qkvb, msc, invl, out_w0);
    // 6) out-proj (all scales) -> yallb
    gemm_ms<2><<<dim3(120, 2), 256, 0, stream>>>(ob, oT, outB, yallb);
    // 7) upsample (all scales) -> ccatb
    upsample_ms<<<8192, 256, 0, stream>>>(yallb, ccatb);
    // 8) fusion GEMM -> fp32 d_out, then LN
    gemm_fus<<<dim3(64, 8), 256, 0, stream>>>(ccatb, fT, fusB, fused);
    ln_kernel<<<8192, 256, 0, stream>>>(fused, lnG, lnB);
}